// Round 1
// baseline (5749.068 us; speedup 1.0000x reference)
//
#include <hip/hip_runtime.h>

// Problem constants: T=128, B=64, D=1024, H=1024. fp32 throughout (the
// recurrence is chaotic: per-step gate noise amplifies ~1e3x over 128 steps;
// fp32 order-noise lands at ~4e-3 absmax, bf16 would fail the 2e-2 gate).
#define TT 128
#define BB 64
#define DD 1024
#define HH 1024
#define G4 4096          // 4*H
#define MM (TT*BB)       // 8192 rows of X flattened
#define BH (BB*HH)       // 65536, one timestep of h/out

#define NWG 512          // persistent grid: exactly 2 blocks per CU (16 waves)
#define RPAD 520         // red row pad: 520%32==8 -> reader gather is 2-way (free)

typedef float f32x4 __attribute__((ext_vector_type(4)));

__device__ __forceinline__ float hsig(float x) {
    x += 0.5f;
    return fminf(fmaxf(x, 0.0f), 1.0f);
}
__device__ __forceinline__ float htanh(float x) {
    return fminf(fmaxf(x, -1.0f), 1.0f);
}

// ---------------------------------------------------------------------------
__global__ void zero_bar(unsigned* p) {
    p[threadIdx.x] = 0u;   // flags[512]
}

// ---------------------------------------------------------------------------
// Gx[8192][4096] = X[8192][1024] @ Wx[1024][4096] + bias  (proven, ~810 us)
__global__ __launch_bounds__(256) void gx_gemm(const float* __restrict__ X,
                                               const float* __restrict__ W,
                                               const float* __restrict__ bias,
                                               float* __restrict__ C) {
    __shared__ float As[16][132];
    __shared__ float Bs[16][132];

    const int tid = threadIdx.x;
    const int tx = tid & 15;
    const int ty = tid >> 4;
    const int m0 = blockIdx.y * 128;
    const int n0 = blockIdx.x * 128;

    float acc[8][8] = {};
    float4 ra[2], rb[2];

    #pragma unroll
    for (int i = 0; i < 2; ++i) {
        int f4 = tid + i * 256;
        ra[i] = *(const float4*)(X + (size_t)(m0 + (f4 >> 2)) * DD + (f4 & 3) * 4);
        rb[i] = *(const float4*)(W + (size_t)(f4 >> 5) * G4 + n0 + (f4 & 31) * 4);
    }

    for (int k0 = 0; k0 < DD; k0 += 16) {
        #pragma unroll
        for (int i = 0; i < 2; ++i) {
            int f4 = tid + i * 256;
            int mi = f4 >> 2, kq = f4 & 3;
            As[kq * 4 + 0][mi] = ra[i].x;
            As[kq * 4 + 1][mi] = ra[i].y;
            As[kq * 4 + 2][mi] = ra[i].z;
            As[kq * 4 + 3][mi] = ra[i].w;
            *(float4*)&Bs[f4 >> 5][(f4 & 31) * 4] = rb[i];
        }
        __syncthreads();

        const int kn = (k0 + 16 < DD) ? (k0 + 16) : k0;
        #pragma unroll
        for (int i = 0; i < 2; ++i) {
            int f4 = tid + i * 256;
            ra[i] = *(const float4*)(X + (size_t)(m0 + (f4 >> 2)) * DD + kn + (f4 & 3) * 4);
            rb[i] = *(const float4*)(W + (size_t)(kn + (f4 >> 5)) * G4 + n0 + (f4 & 31) * 4);
        }

        #pragma unroll
        for (int kk = 0; kk < 16; ++kk) {
            float ar[8], br[8];
            *(float4*)&ar[0] = *(const float4*)&As[kk][ty * 4];
            *(float4*)&ar[4] = *(const float4*)&As[kk][64 + ty * 4];
            *(float4*)&br[0] = *(const float4*)&Bs[kk][tx * 4];
            *(float4*)&br[4] = *(const float4*)&Bs[kk][64 + tx * 4];
            #pragma unroll
            for (int i = 0; i < 8; ++i)
                #pragma unroll
                for (int j = 0; j < 8; ++j)
                    acc[i][j] += ar[i] * br[j];
        }
        __syncthreads();
    }

    float bl[8];
    *(float4*)&bl[0] = *(const float4*)(bias + n0 + tx * 4);
    *(float4*)&bl[4] = *(const float4*)(bias + n0 + 64 + tx * 4);
    #pragma unroll
    for (int i = 0; i < 8; ++i) {
        int mrow = m0 + ty * 4 + (i & 3) + 64 * (i >> 2);
        float* crow = C + (size_t)mrow * G4 + n0;
        float4 o1, o2;
        o1.x = acc[i][0] + bl[0]; o1.y = acc[i][1] + bl[1];
        o1.z = acc[i][2] + bl[2]; o1.w = acc[i][3] + bl[3];
        o2.x = acc[i][4] + bl[4]; o2.y = acc[i][5] + bl[5];
        o2.z = acc[i][6] + bl[6]; o2.w = acc[i][7] + bl[7];
        *(float4*)(crow + tx * 4) = o1;
        *(float4*)(crow + 64 + tx * 4) = o2;
    }
}

// ---------------------------------------------------------------------------
// Persistent recurrence, 2 wgs per CU (the occupancy fix: 16 waves/CU so two
// phase-decorrelated wgs interleave L2/LDS/VALU pipes; per-CU pipe floors are
// unchanged vs the 1-wg layout). FENCE-FREE cross-wg h exchange: h crosses wg
// boundaries as agent-scope relaxed stores + sc0sc1 dwordx4 loads (bypass
// L1/L2, served by Infinity Cache). No __threadfence in the loop -> L2 never
// invalidated -> Wh stays L2-resident (2 MB/XCD under bx%8 = hct%8
// round-robin heuristic; correctness is placement-free).
// Partition: 512 wgs = 8 btiles (8 batch rows) x 64 hcts (16 H-cols = 64
// gate-cols). Sync domain per btile: 64 producer flags, direct all-gather.
// Ordering: h atomic stores -> s_waitcnt vmcnt(0) -> __syncthreads -> flag.
// __launch_bounds__(512,4) pins VGPR<=128: REQUIRED so all 512 wgs are
// co-resident (LDS 68.6KB*2 <= 160KB; 1 wg/CU would deadlock the flag sync).
__global__ __launch_bounds__(512, 4) void lstm_persist(const float* __restrict__ Gx,
                                                       const float* __restrict__ Wh,
                                                       float* __restrict__ out,
                                                       unsigned* __restrict__ flags) {
    // union: hs = [8 b][1152] = 9216 | red = [32 vidx][520] = 16640 ; +gsum[512]
    __shared__ float smem[16640 + 512];
    float* hs   = smem;
    float* red  = smem;
    float* gsum = smem + 16640;

    const int tid   = threadIdx.x;
    const int btile = blockIdx.x >> 6;     // 0..7
    const int hct   = blockIdx.x & 63;     // 0..63
    const int b0  = btile * 8;
    const int hc0 = hct * 16;

    // matmul thread identity: kc = 16-k chunk (0..63), tt = 8 gate-cols (0..7)
    const int kc = tid >> 3;
    const int tt = tid & 7;
    const int gate_m = tt >> 1;            // 0..3
    const int sub = (tt & 1) * 8;          // 0 or 8 within the 16-col block
    const float* wbase = Wh + (size_t)(kc * 16) * G4 + gate_m * HH + hc0 + sub;
    const int hbase = (kc >> 1) * 36 + (kc & 1) * 16;   // skewed hs k-offset

    // cell identity (tid<128): one (b, hcol) cell per thread, c in creg
    const bool cell_act = (tid < 128);
    const int cb  = tid >> 4;              // 0..7 local b
    const int chc = tid & 15;              // 0..15 local h col
    const size_t cell_g = (size_t)(b0 + cb) * G4 + hc0 + chc;
    const size_t cell_h = (size_t)(b0 + cb) * HH + hc0 + chc;
    float creg = 0.0f;

    unsigned* gflags = flags + btile * 64; // this btile group's 64 flags

    // ---- t = 0: gates = Gx[0] (h0 = c0 = 0); publish h(0) through IC
    if (cell_act) {
        const float* gr = Gx + cell_g;
        float ii = hsig(gr[0]);
        float gv = htanh(gr[2 * HH]);
        float oo = hsig(gr[3 * HH]);
        creg = ii * gv;
        __hip_atomic_store(out + cell_h, oo * htanh(creg),
                           __ATOMIC_RELAXED, __HIP_MEMORY_SCOPE_AGENT);
    }
    asm volatile("s_waitcnt vmcnt(0)" ::: "memory");
    __syncthreads();
    if (tid == 0)
        __hip_atomic_store(gflags + hct, 1u, __ATOMIC_RELAXED,
                           __HIP_MEMORY_SCOPE_AGENT);

    for (int t = 1; t < TT; ++t) {
        // prefetch this step's Gx gate values (own data; overlaps the wait)
        float gi = 0.f, gf = 0.f, gg = 0.f, go = 0.f;
        if (cell_act) {
            const float* gr = Gx + (size_t)t * BB * G4 + cell_g;
            gi = gr[0];
            gf = gr[HH];
            gg = gr[2 * HH];
            go = gr[3 * HH];
        }

        // ---- group barrier: wait for all 64 producers of h(t-1)
        if (tid < 64) {
            while (__hip_atomic_load(gflags + tid, __ATOMIC_RELAXED,
                                     __HIP_MEMORY_SCOPE_AGENT) < (unsigned)t)
                __builtin_amdgcn_s_sleep(1);
        }
        __syncthreads();

        // ---- stage h(t-1)[b0..b0+7][:] -> skewed hs via 16B IC-coherent
        // loads (sc0 sc1 = same coherence bits as the dword atomic loads,
        // 4x wider). waitcnt lives inside the asm block with its loads.
        {
            const float* hprev = out + (size_t)(t - 1) * BH;
            const float* sp[4];
            int wbi[4], wq[4];
            #pragma unroll
            for (int i = 0; i < 4; ++i) {
                int idx4 = tid + i * 512;          // 0..2047 float4 slots
                wbi[i] = idx4 >> 8;                // 0..7 local b
                wq[i]  = (idx4 & 255) * 4;         // 0..1020, %4==0
                sp[i]  = hprev + (size_t)(b0 + wbi[i]) * HH + wq[i];
            }
            f32x4 v0, v1, v2, v3;
            asm volatile(
                "global_load_dwordx4 %0, %4, off sc0 sc1\n\t"
                "global_load_dwordx4 %1, %5, off sc0 sc1\n\t"
                "global_load_dwordx4 %2, %6, off sc0 sc1\n\t"
                "global_load_dwordx4 %3, %7, off sc0 sc1\n\t"
                "s_waitcnt vmcnt(0)"
                : "=&v"(v0), "=&v"(v1), "=&v"(v2), "=&v"(v3)
                : "v"(sp[0]), "v"(sp[1]), "v"(sp[2]), "v"(sp[3])
                : "memory");
            *(f32x4*)&hs[wbi[0] * 1152 + (wq[0] >> 5) * 36 + (wq[0] & 31)] = v0;
            *(f32x4*)&hs[wbi[1] * 1152 + (wq[1] >> 5) * 36 + (wq[1] & 31)] = v1;
            *(f32x4*)&hs[wbi[2] * 1152 + (wq[2] >> 5) * 36 + (wq[2] & 31)] = v2;
            *(f32x4*)&hs[wbi[3] * 1152 + (wq[3] >> 5) * 36 + (wq[3] & 31)] = v3;
        }
        __syncthreads();

        // ---- FMA: acc[8 b][8 gc] over k in [kc*16, kc*16+16)
        float acc[8][8] = {};
        const float* wp = wbase;
        #pragma unroll 2
        for (int k4 = 0; k4 < 4; ++k4) {
            f32x4 hv[8];
            #pragma unroll
            for (int bi = 0; bi < 8; ++bi)
                hv[bi] = *(const f32x4*)&hs[bi * 1152 + hbase + k4 * 4];
            #pragma unroll
            for (int j = 0; j < 4; ++j) {
                f32x4 w0 = *(const f32x4*)(wp);
                f32x4 w1 = *(const f32x4*)(wp + 4);
                wp += G4;
                #pragma unroll
                for (int bi = 0; bi < 8; ++bi) {
                    float h = hv[bi][j];
                    acc[bi][0] += h * w0[0];
                    acc[bi][1] += h * w0[1];
                    acc[bi][2] += h * w0[2];
                    acc[bi][3] += h * w0[3];
                    acc[bi][4] += h * w1[0];
                    acc[bi][5] += h * w1[1];
                    acc[bi][6] += h * w1[2];
                    acc[bi][7] += h * w1[3];
                }
            }
        }
        __syncthreads();                   // hs dead; smem becomes red

        // ---- two rounds (4 b each): stage partials, 64-deep gather.
        // write: red[v][tid] consecutive-tid, conflict-free.
        // read: addr%32 = vidx*8+rtt (RPAD%32==8) -> exactly 2-way = free.
        #pragma unroll
        for (int round = 0; round < 2; ++round) {
            #pragma unroll
            for (int bi = 0; bi < 4; ++bi)
                #pragma unroll
                for (int j = 0; j < 8; ++j)
                    red[(size_t)(bi * 8 + j) * RPAD + tid] = acc[round * 4 + bi][j];
            __syncthreads();
            if ((tid >> 8) == round) {     // 256 readers = 4 full waves
                const int r2  = tid & 255;
                const int rb  = r2 >> 6;               // b&3
                const int gc  = r2 & 63;               // gate*16 + hc
                const int rhc = gc & 15;
                const int rtt = (gc >> 4) * 2 + (rhc >> 3);
                const int vidx = rb * 8 + (rhc & 7);
                const float* rp = red + (size_t)vidx * RPAD + rtt;
                float s0 = 0.f, s1 = 0.f, s2 = 0.f, s3 = 0.f;
                #pragma unroll
                for (int k2 = 0; k2 < 64; k2 += 4) {
                    s0 += rp[(k2 + 0) * 8];
                    s1 += rp[(k2 + 1) * 8];
                    s2 += rp[(k2 + 2) * 8];
                    s3 += rp[(k2 + 3) * 8];
                }
                gsum[(round * 4 + rb) * 64 + gc] = (s0 + s1) + (s2 + s3);
            }
            __syncthreads();
        }

        // ---- cell update (thread-local c); publish h through IC
        if (cell_act) {
            float ii = hsig(gi + gsum[cb * 64 + chc]);
            float ff = hsig(gf + gsum[cb * 64 + 16 + chc]);
            float gv = htanh(gg + gsum[cb * 64 + 32 + chc]);
            float oo = hsig(go + gsum[cb * 64 + 48 + chc]);
            creg = ff * creg + ii * gv;
            __hip_atomic_store(out + (size_t)t * BH + cell_h, oo * htanh(creg),
                               __ATOMIC_RELAXED, __HIP_MEMORY_SCOPE_AGENT);
        }
        asm volatile("s_waitcnt vmcnt(0)" ::: "memory");
        __syncthreads();
        if (tid == 0)
            __hip_atomic_store(gflags + hct, (unsigned)(t + 1),
                               __ATOMIC_RELAXED, __HIP_MEMORY_SCOPE_AGENT);
    }
}

// ---------------------------------------------------------------------------
extern "C" void kernel_launch(void* const* d_in, const int* in_sizes, int n_in,
                              void* d_out, int out_size, void* d_ws, size_t ws_size,
                              hipStream_t stream) {
    const float* x  = (const float*)d_in[0];   // [T,B,D]
    const float* Wx = (const float*)d_in[1];   // [D,4H]
    const float* Wh = (const float*)d_in[2];   // [H,4H]
    const float* bs = (const float*)d_in[3];   // [4H]
    float* out = (float*)d_out;                // [T,B,H] — doubles as h history

    // ws layout (floats): Gx 33,554,432 | flags (512 u32)
    float* Gx = (float*)d_ws;
    unsigned* flags = (unsigned*)(Gx + (size_t)MM * G4);

    zero_bar<<<dim3(1), dim3(512), 0, stream>>>(flags);

    // Gx = X @ Wx + b for all timesteps at once
    gx_gemm<<<dim3(G4 / 128, MM / 128), dim3(256), 0, stream>>>(x, Wx, bs, Gx);

    // all 128 recurrent steps in one plain-launch persistent kernel
    lstm_persist<<<dim3(NWG), dim3(512), 0, stream>>>(Gx, Wh, out, flags);
}

// Round 2
// 4386.919 us; speedup vs baseline: 1.3105x; 1.3105x over previous
//
#include <hip/hip_runtime.h>

// Problem constants: T=128, B=64, D=1024, H=1024. fp32 throughout (the
// recurrence is chaotic: per-step gate noise amplifies ~1e3x over 128 steps;
// fp32 order-noise lands at ~4e-3 absmax, bf16 would fail the 2e-2 gate).
#define TT 128
#define BB 64
#define DD 1024
#define HH 1024
#define G4 4096          // 4*H
#define MM (TT*BB)       // 8192 rows of X flattened
#define BH (BB*HH)       // 65536, one timestep of h/out

#define NWG 512          // persistent grid: exactly 2 blocks per CU (16 waves)
#define RPAD 520         // red row pad: 520%32==8 -> reader gather is 2-way (free)

typedef float f32x4 __attribute__((ext_vector_type(4)));

__device__ __forceinline__ float hsig(float x) {
    x += 0.5f;
    return fminf(fmaxf(x, 0.0f), 1.0f);
}
__device__ __forceinline__ float htanh(float x) {
    return fminf(fmaxf(x, -1.0f), 1.0f);
}

// ---------------------------------------------------------------------------
__global__ void zero_bar(unsigned* p) {
    p[threadIdx.x] = 0u;   // flags[512]
}

// ---------------------------------------------------------------------------
// Gx[8192][4096] = X[8192][1024] @ Wx[1024][4096] + bias  (proven, ~810 us)
__global__ __launch_bounds__(256) void gx_gemm(const float* __restrict__ X,
                                               const float* __restrict__ W,
                                               const float* __restrict__ bias,
                                               float* __restrict__ C) {
    __shared__ float As[16][132];
    __shared__ float Bs[16][132];

    const int tid = threadIdx.x;
    const int tx = tid & 15;
    const int ty = tid >> 4;
    const int m0 = blockIdx.y * 128;
    const int n0 = blockIdx.x * 128;

    float acc[8][8] = {};
    float4 ra[2], rb[2];

    #pragma unroll
    for (int i = 0; i < 2; ++i) {
        int f4 = tid + i * 256;
        ra[i] = *(const float4*)(X + (size_t)(m0 + (f4 >> 2)) * DD + (f4 & 3) * 4);
        rb[i] = *(const float4*)(W + (size_t)(f4 >> 5) * G4 + n0 + (f4 & 31) * 4);
    }

    for (int k0 = 0; k0 < DD; k0 += 16) {
        #pragma unroll
        for (int i = 0; i < 2; ++i) {
            int f4 = tid + i * 256;
            int mi = f4 >> 2, kq = f4 & 3;
            As[kq * 4 + 0][mi] = ra[i].x;
            As[kq * 4 + 1][mi] = ra[i].y;
            As[kq * 4 + 2][mi] = ra[i].z;
            As[kq * 4 + 3][mi] = ra[i].w;
            *(float4*)&Bs[f4 >> 5][(f4 & 31) * 4] = rb[i];
        }
        __syncthreads();

        const int kn = (k0 + 16 < DD) ? (k0 + 16) : k0;
        #pragma unroll
        for (int i = 0; i < 2; ++i) {
            int f4 = tid + i * 256;
            ra[i] = *(const float4*)(X + (size_t)(m0 + (f4 >> 2)) * DD + kn + (f4 & 3) * 4);
            rb[i] = *(const float4*)(W + (size_t)(kn + (f4 >> 5)) * G4 + n0 + (f4 & 31) * 4);
        }

        #pragma unroll
        for (int kk = 0; kk < 16; ++kk) {
            float ar[8], br[8];
            *(float4*)&ar[0] = *(const float4*)&As[kk][ty * 4];
            *(float4*)&ar[4] = *(const float4*)&As[kk][64 + ty * 4];
            *(float4*)&br[0] = *(const float4*)&Bs[kk][tx * 4];
            *(float4*)&br[4] = *(const float4*)&Bs[kk][64 + tx * 4];
            #pragma unroll
            for (int i = 0; i < 8; ++i)
                #pragma unroll
                for (int j = 0; j < 8; ++j)
                    acc[i][j] += ar[i] * br[j];
        }
        __syncthreads();
    }

    float bl[8];
    *(float4*)&bl[0] = *(const float4*)(bias + n0 + tx * 4);
    *(float4*)&bl[4] = *(const float4*)(bias + n0 + 64 + tx * 4);
    #pragma unroll
    for (int i = 0; i < 8; ++i) {
        int mrow = m0 + ty * 4 + (i & 3) + 64 * (i >> 2);
        float* crow = C + (size_t)mrow * G4 + n0;
        float4 o1, o2;
        o1.x = acc[i][0] + bl[0]; o1.y = acc[i][1] + bl[1];
        o1.z = acc[i][2] + bl[2]; o1.w = acc[i][3] + bl[3];
        o2.x = acc[i][4] + bl[4]; o2.y = acc[i][5] + bl[5];
        o2.z = acc[i][6] + bl[6]; o2.w = acc[i][7] + bl[7];
        *(float4*)(crow + tx * 4) = o1;
        *(float4*)(crow + 64 + tx * 4) = o2;
    }
}

// ---------------------------------------------------------------------------
// Persistent recurrence, 2 wgs per CU (16 waves/CU: two phase-decorrelated
// wgs interleave the L2/LDS/VALU pipes that serialize behind barriers in a
// single wg; per-CU pipe floors are unchanged vs the 1-wg layout).
// FENCE-FREE cross-wg h exchange: h crosses wg boundaries as agent-scope
// relaxed stores + sc0sc1 dwordx4 loads (bypass L1/L2, served by Infinity
// Cache). No __threadfence in the loop -> L2 never invalidated -> Wh stays
// L2-resident. Partition: 512 wgs = 8 btiles (8 batch rows) x 64 hcts
// (16 H-cols = 64 gate-cols). Sync domain per btile: 64 producer flags.
// Ordering: h atomic stores -> s_waitcnt vmcnt(0) -> __syncthreads -> flag.
//
// __launch_bounds__(512, 2): EMPIRICAL SEMANTICS — 2nd arg is min BLOCKS/CU
// (CUDA-style). Round-1 measured (512,4) -> VGPR_Count=64 (= 8 waves/EU cap,
// i.e. 4 blocks x 8 waves / 4 SIMDs), which spilled acc[8][8] to scratch
// (FETCH_SIZE 206MB -> 7.9GB, 2.6x regression). (512,2) -> 4 waves/EU ->
// VGPR cap 128; round-0 proved this matmul structure fits exactly 128 with
// zero scratch. 2 blocks/CU co-residency (LDS 68.6KB*2 <= 160KB) is REQUIRED
// so the flag sync cannot starve.
__global__ __launch_bounds__(512, 2) void lstm_persist(const float* __restrict__ Gx,
                                                       const float* __restrict__ Wh,
                                                       float* __restrict__ out,
                                                       unsigned* __restrict__ flags) {
    // union: hs = [8 b][1152] = 9216 | red = [32 vidx][520] = 16640 ; +gsum[512]
    __shared__ float smem[16640 + 512];
    float* hs   = smem;
    float* red  = smem;
    float* gsum = smem + 16640;

    const int tid   = threadIdx.x;
    const int btile = blockIdx.x >> 6;     // 0..7
    const int hct   = blockIdx.x & 63;     // 0..63
    const int b0  = btile * 8;
    const int hc0 = hct * 16;

    // matmul thread identity: kc = 16-k chunk (0..63), tt = 8 gate-cols (0..7)
    const int kc = tid >> 3;
    const int tt = tid & 7;
    const int gate_m = tt >> 1;            // 0..3
    const int sub = (tt & 1) * 8;          // 0 or 8 within the 16-col block
    const float* wbase = Wh + (size_t)(kc * 16) * G4 + gate_m * HH + hc0 + sub;
    const int hbase = (kc >> 1) * 36 + (kc & 1) * 16;   // skewed hs k-offset

    // cell identity (tid<128): one (b, hcol) cell per thread, c in creg
    const bool cell_act = (tid < 128);
    const int cb  = tid >> 4;              // 0..7 local b
    const int chc = tid & 15;              // 0..15 local h col
    const size_t cell_g = (size_t)(b0 + cb) * G4 + hc0 + chc;
    const size_t cell_h = (size_t)(b0 + cb) * HH + hc0 + chc;
    float creg = 0.0f;

    unsigned* gflags = flags + btile * 64; // this btile group's 64 flags

    // ---- t = 0: gates = Gx[0] (h0 = c0 = 0); publish h(0) through IC
    if (cell_act) {
        const float* gr = Gx + cell_g;
        float ii = hsig(gr[0]);
        float gv = htanh(gr[2 * HH]);
        float oo = hsig(gr[3 * HH]);
        creg = ii * gv;
        __hip_atomic_store(out + cell_h, oo * htanh(creg),
                           __ATOMIC_RELAXED, __HIP_MEMORY_SCOPE_AGENT);
    }
    asm volatile("s_waitcnt vmcnt(0)" ::: "memory");
    __syncthreads();
    if (tid == 0)
        __hip_atomic_store(gflags + hct, 1u, __ATOMIC_RELAXED,
                           __HIP_MEMORY_SCOPE_AGENT);

    for (int t = 1; t < TT; ++t) {
        // prefetch this step's Gx gate values (own data; overlaps the wait)
        float gi = 0.f, gf = 0.f, gg = 0.f, go = 0.f;
        if (cell_act) {
            const float* gr = Gx + (size_t)t * BB * G4 + cell_g;
            gi = gr[0];
            gf = gr[HH];
            gg = gr[2 * HH];
            go = gr[3 * HH];
        }

        // ---- group barrier: wait for all 64 producers of h(t-1)
        if (tid < 64) {
            while (__hip_atomic_load(gflags + tid, __ATOMIC_RELAXED,
                                     __HIP_MEMORY_SCOPE_AGENT) < (unsigned)t)
                __builtin_amdgcn_s_sleep(1);
        }
        __syncthreads();

        // ---- stage h(t-1)[b0..b0+7][:] -> skewed hs via 16B IC-coherent
        // loads (sc0 sc1 = same coherence bits as the dword atomic loads,
        // 4x wider). waitcnt lives inside the asm block with its loads.
        {
            const float* hprev = out + (size_t)(t - 1) * BH;
            const float* sp[4];
            int wbi[4], wq[4];
            #pragma unroll
            for (int i = 0; i < 4; ++i) {
                int idx4 = tid + i * 512;          // 0..2047 float4 slots
                wbi[i] = idx4 >> 8;                // 0..7 local b
                wq[i]  = (idx4 & 255) * 4;         // 0..1020, %4==0
                sp[i]  = hprev + (size_t)(b0 + wbi[i]) * HH + wq[i];
            }
            f32x4 v0, v1, v2, v3;
            asm volatile(
                "global_load_dwordx4 %0, %4, off sc0 sc1\n\t"
                "global_load_dwordx4 %1, %5, off sc0 sc1\n\t"
                "global_load_dwordx4 %2, %6, off sc0 sc1\n\t"
                "global_load_dwordx4 %3, %7, off sc0 sc1\n\t"
                "s_waitcnt vmcnt(0)"
                : "=&v"(v0), "=&v"(v1), "=&v"(v2), "=&v"(v3)
                : "v"(sp[0]), "v"(sp[1]), "v"(sp[2]), "v"(sp[3])
                : "memory");
            *(f32x4*)&hs[wbi[0] * 1152 + (wq[0] >> 5) * 36 + (wq[0] & 31)] = v0;
            *(f32x4*)&hs[wbi[1] * 1152 + (wq[1] >> 5) * 36 + (wq[1] & 31)] = v1;
            *(f32x4*)&hs[wbi[2] * 1152 + (wq[2] >> 5) * 36 + (wq[2] & 31)] = v2;
            *(f32x4*)&hs[wbi[3] * 1152 + (wq[3] >> 5) * 36 + (wq[3] & 31)] = v3;
        }
        __syncthreads();

        // ---- FMA: acc[8 b][8 gc] over k in [kc*16, kc*16+16)
        float acc[8][8] = {};
        const float* wp = wbase;
        #pragma unroll 2
        for (int k4 = 0; k4 < 4; ++k4) {
            f32x4 hv[8];
            #pragma unroll
            for (int bi = 0; bi < 8; ++bi)
                hv[bi] = *(const f32x4*)&hs[bi * 1152 + hbase + k4 * 4];
            #pragma unroll
            for (int j = 0; j < 4; ++j) {
                f32x4 w0 = *(const f32x4*)(wp);
                f32x4 w1 = *(const f32x4*)(wp + 4);
                wp += G4;
                #pragma unroll
                for (int bi = 0; bi < 8; ++bi) {
                    float h = hv[bi][j];
                    acc[bi][0] += h * w0[0];
                    acc[bi][1] += h * w0[1];
                    acc[bi][2] += h * w0[2];
                    acc[bi][3] += h * w0[3];
                    acc[bi][4] += h * w1[0];
                    acc[bi][5] += h * w1[1];
                    acc[bi][6] += h * w1[2];
                    acc[bi][7] += h * w1[3];
                }
            }
        }
        __syncthreads();                   // hs dead; smem becomes red

        // ---- two rounds (4 b each): stage partials, 64-deep gather.
        // write: red[v][tid] consecutive-tid, conflict-free.
        // read: addr%32 = vidx*8+rtt (RPAD%32==8) -> exactly 2-way = free.
        #pragma unroll
        for (int round = 0; round < 2; ++round) {
            #pragma unroll
            for (int bi = 0; bi < 4; ++bi)
                #pragma unroll
                for (int j = 0; j < 8; ++j)
                    red[(size_t)(bi * 8 + j) * RPAD + tid] = acc[round * 4 + bi][j];
            __syncthreads();
            if ((tid >> 8) == round) {     // 256 readers = 4 full waves
                const int r2  = tid & 255;
                const int rb  = r2 >> 6;               // b&3
                const int gc  = r2 & 63;               // gate*16 + hc
                const int rhc = gc & 15;
                const int rtt = (gc >> 4) * 2 + (rhc >> 3);
                const int vidx = rb * 8 + (rhc & 7);
                const float* rp = red + (size_t)vidx * RPAD + rtt;
                float s0 = 0.f, s1 = 0.f, s2 = 0.f, s3 = 0.f;
                #pragma unroll
                for (int k2 = 0; k2 < 64; k2 += 4) {
                    s0 += rp[(k2 + 0) * 8];
                    s1 += rp[(k2 + 1) * 8];
                    s2 += rp[(k2 + 2) * 8];
                    s3 += rp[(k2 + 3) * 8];
                }
                gsum[(round * 4 + rb) * 64 + gc] = (s0 + s1) + (s2 + s3);
            }
            __syncthreads();
        }

        // ---- cell update (thread-local c); publish h through IC
        if (cell_act) {
            float ii = hsig(gi + gsum[cb * 64 + chc]);
            float ff = hsig(gf + gsum[cb * 64 + 16 + chc]);
            float gv = htanh(gg + gsum[cb * 64 + 32 + chc]);
            float oo = hsig(go + gsum[cb * 64 + 48 + chc]);
            creg = ff * creg + ii * gv;
            __hip_atomic_store(out + (size_t)t * BH + cell_h, oo * htanh(creg),
                               __ATOMIC_RELAXED, __HIP_MEMORY_SCOPE_AGENT);
        }
        asm volatile("s_waitcnt vmcnt(0)" ::: "memory");
        __syncthreads();
        if (tid == 0)
            __hip_atomic_store(gflags + hct, (unsigned)(t + 1),
                               __ATOMIC_RELAXED, __HIP_MEMORY_SCOPE_AGENT);
    }
}

// ---------------------------------------------------------------------------
extern "C" void kernel_launch(void* const* d_in, const int* in_sizes, int n_in,
                              void* d_out, int out_size, void* d_ws, size_t ws_size,
                              hipStream_t stream) {
    const float* x  = (const float*)d_in[0];   // [T,B,D]
    const float* Wx = (const float*)d_in[1];   // [D,4H]
    const float* Wh = (const float*)d_in[2];   // [H,4H]
    const float* bs = (const float*)d_in[3];   // [4H]
    float* out = (float*)d_out;                // [T,B,H] — doubles as h history

    // ws layout (floats): Gx 33,554,432 | flags (512 u32)
    float* Gx = (float*)d_ws;
    unsigned* flags = (unsigned*)(Gx + (size_t)MM * G4);

    zero_bar<<<dim3(1), dim3(512), 0, stream>>>(flags);

    // Gx = X @ Wx + b for all timesteps at once
    gx_gemm<<<dim3(G4 / 128, MM / 128), dim3(256), 0, stream>>>(x, Wx, bs, Gx);

    // all 128 recurrent steps in one plain-launch persistent kernel
    lstm_persist<<<dim3(NWG), dim3(512), 0, stream>>>(Gx, Wh, out, flags);
}

// Round 3
// 3332.587 us; speedup vs baseline: 1.7251x; 1.3164x over previous
//
#include <hip/hip_runtime.h>

// Problem constants: T=128, B=64, D=1024, H=1024. fp32 throughout (the
// recurrence is chaotic: per-step gate noise amplifies ~1e3x over 128 steps;
// fp32 order-noise lands at ~4e-3 absmax, bf16 would fail the 2e-2 gate).
#define TT 128
#define BB 64
#define DD 1024
#define HH 1024
#define G4 4096          // 4*H
#define MM (TT*BB)       // 8192 rows of X flattened
#define BH (BB*HH)       // 65536, one timestep of h/out

#define NWG 512          // persistent grid: 2 blocks per CU (16 waves)
#define RPAD 520         // red row pad: 520%32==8 -> reader gather is 2-way (free)

typedef float f32x4 __attribute__((ext_vector_type(4)));

__device__ __forceinline__ float hsig(float x) {
    x += 0.5f;
    return fminf(fmaxf(x, 0.0f), 1.0f);
}
__device__ __forceinline__ float htanh(float x) {
    return fminf(fmaxf(x, -1.0f), 1.0f);
}

// ---------------------------------------------------------------------------
__global__ void zero_bar(unsigned* p) {
    p[threadIdx.x] = 0u;   // flags[512]
}

// ---------------------------------------------------------------------------
// Gx[8192][4096] = X[8192][1024] @ Wx[1024][4096] + bias  (proven, ~810 us)
__global__ __launch_bounds__(256) void gx_gemm(const float* __restrict__ X,
                                               const float* __restrict__ W,
                                               const float* __restrict__ bias,
                                               float* __restrict__ C) {
    __shared__ float As[16][132];
    __shared__ float Bs[16][132];

    const int tid = threadIdx.x;
    const int tx = tid & 15;
    const int ty = tid >> 4;
    const int m0 = blockIdx.y * 128;
    const int n0 = blockIdx.x * 128;

    float acc[8][8] = {};
    float4 ra[2], rb[2];

    #pragma unroll
    for (int i = 0; i < 2; ++i) {
        int f4 = tid + i * 256;
        ra[i] = *(const float4*)(X + (size_t)(m0 + (f4 >> 2)) * DD + (f4 & 3) * 4);
        rb[i] = *(const float4*)(W + (size_t)(f4 >> 5) * G4 + n0 + (f4 & 31) * 4);
    }

    for (int k0 = 0; k0 < DD; k0 += 16) {
        #pragma unroll
        for (int i = 0; i < 2; ++i) {
            int f4 = tid + i * 256;
            int mi = f4 >> 2, kq = f4 & 3;
            As[kq * 4 + 0][mi] = ra[i].x;
            As[kq * 4 + 1][mi] = ra[i].y;
            As[kq * 4 + 2][mi] = ra[i].z;
            As[kq * 4 + 3][mi] = ra[i].w;
            *(float4*)&Bs[f4 >> 5][(f4 & 31) * 4] = rb[i];
        }
        __syncthreads();

        const int kn = (k0 + 16 < DD) ? (k0 + 16) : k0;
        #pragma unroll
        for (int i = 0; i < 2; ++i) {
            int f4 = tid + i * 256;
            ra[i] = *(const float4*)(X + (size_t)(m0 + (f4 >> 2)) * DD + kn + (f4 & 3) * 4);
            rb[i] = *(const float4*)(W + (size_t)(kn + (f4 >> 5)) * G4 + n0 + (f4 & 31) * 4);
        }

        #pragma unroll
        for (int kk = 0; kk < 16; ++kk) {
            float ar[8], br[8];
            *(float4*)&ar[0] = *(const float4*)&As[kk][ty * 4];
            *(float4*)&ar[4] = *(const float4*)&As[kk][64 + ty * 4];
            *(float4*)&br[0] = *(const float4*)&Bs[kk][tx * 4];
            *(float4*)&br[4] = *(const float4*)&Bs[kk][64 + tx * 4];
            #pragma unroll
            for (int i = 0; i < 8; ++i)
                #pragma unroll
                for (int j = 0; j < 8; ++j)
                    acc[i][j] += ar[i] * br[j];
        }
        __syncthreads();
    }

    float bl[8];
    *(float4*)&bl[0] = *(const float4*)(bias + n0 + tx * 4);
    *(float4*)&bl[4] = *(const float4*)(bias + n0 + 64 + tx * 4);
    #pragma unroll
    for (int i = 0; i < 8; ++i) {
        int mrow = m0 + ty * 4 + (i & 3) + 64 * (i >> 2);
        float* crow = C + (size_t)mrow * G4 + n0;
        float4 o1, o2;
        o1.x = acc[i][0] + bl[0]; o1.y = acc[i][1] + bl[1];
        o1.z = acc[i][2] + bl[2]; o1.w = acc[i][3] + bl[3];
        o2.x = acc[i][4] + bl[4]; o2.y = acc[i][5] + bl[5];
        o2.z = acc[i][6] + bl[6]; o2.w = acc[i][7] + bl[7];
        *(float4*)(crow + tx * 4) = o1;
        *(float4*)(crow + 64 + tx * 4) = o2;
    }
}

// ---------------------------------------------------------------------------
// Persistent recurrence, 2 blocks per CU (16 waves). OCCUPANCY RULE measured
// on this chip (rounds 0-2): a second 512-thread block becomes resident only
// if VGPR < 128 (r1: VGPR=64 -> 45.6% occ; r0/r2: VGPR=128 -> 24.7% occ;
// 16 waves x 128 = 2048 exactly-fills the pool and is rejected). This
// version cuts register demand structurally: 16 tt-groups x 4 gate-cols ->
// acc[8][4]=32 regs (was 64), hv held 1 f32x4 at a time, 4 w-rows=16 regs.
// Peak liveness ~100 -> allocator lands well under 128.
//
// FENCE-FREE cross-wg h exchange: h crosses wg boundaries as agent-scope
// relaxed stores + sc0 (L2-CACHED, L1-bypassed) dwordx4 loads. sc0-only is
// the proven round-0 semantics: consumer L2 lines for out[t-1] are always
// cold (producers write through), so L2 caching is safe AND lets same-btile
// blocks on an XCD share staged h lines (r0: FETCH 206 MB total; r2's sc1
// bypass cost 2.44 GB). No __threadfence -> L2 never invalidated -> Wh stays
// L2-resident. Partition: 512 wgs = 8 btiles (8 batch rows) x 64 hcts
// (16 H-cols). Sync domain per btile: 64 producer flags.
// Ordering: h atomic stores -> s_waitcnt vmcnt(0) -> __syncthreads -> flag.
__global__ __launch_bounds__(512, 2) void lstm_persist(const float* __restrict__ Gx,
                                                       const float* __restrict__ Wh,
                                                       float* __restrict__ out,
                                                       unsigned* __restrict__ flags) {
    // union: hs = [8 b][1152] = 9216 | red = [16 vidx][520] = 8320 ; +gsum[512]
    // total 9728 floats = 38.9 KB -> LDS never the residency limit.
    __shared__ float smem[9216 + 512];
    float* hs   = smem;
    float* red  = smem;
    float* gsum = smem + 9216;

    const int tid   = threadIdx.x;
    const int btile = blockIdx.x >> 6;     // 0..7
    const int hct   = blockIdx.x & 63;     // 0..63
    const int b0  = btile * 8;
    const int hc0 = hct * 16;

    // matmul identity: kc = 32-k chunk (0..31), tt = 4 gate-cols (0..15)
    const int kc = tid >> 4;
    const int tt = tid & 15;
    const int gate_m = tt >> 2;            // 0..3
    const int sub4 = (tt & 3) * 4;         // 0,4,8,12 within the 16-col block
    const float* wbase = Wh + (size_t)(kc * 32) * G4 + gate_m * HH + hc0 + sub4;
    const int hbase = kc * 36;             // skewed hs k-offset (32 floats/chunk)

    // cell identity (tid<128): one (b, hcol) cell per thread, c in creg
    const bool cell_act = (tid < 128);
    const int cb  = tid >> 4;              // 0..7 local b
    const int chc = tid & 15;              // 0..15 local h col
    const size_t cell_g = (size_t)(b0 + cb) * G4 + hc0 + chc;
    const size_t cell_h = (size_t)(b0 + cb) * HH + hc0 + chc;
    float creg = 0.0f;

    unsigned* gflags = flags + btile * 64; // this btile group's 64 flags

    // ---- t = 0: gates = Gx[0] (h0 = c0 = 0); publish h(0) through IC
    if (cell_act) {
        const float* gr = Gx + cell_g;
        float ii = hsig(gr[0]);
        float gv = htanh(gr[2 * HH]);
        float oo = hsig(gr[3 * HH]);
        creg = ii * gv;
        __hip_atomic_store(out + cell_h, oo * htanh(creg),
                           __ATOMIC_RELAXED, __HIP_MEMORY_SCOPE_AGENT);
    }
    asm volatile("s_waitcnt vmcnt(0)" ::: "memory");
    __syncthreads();
    if (tid == 0)
        __hip_atomic_store(gflags + hct, 1u, __ATOMIC_RELAXED,
                           __HIP_MEMORY_SCOPE_AGENT);

    for (int t = 1; t < TT; ++t) {
        // prefetch this step's Gx gate values (own data; overlaps the wait)
        float gi = 0.f, gf = 0.f, gg = 0.f, go = 0.f;
        if (cell_act) {
            const float* gr = Gx + (size_t)t * BB * G4 + cell_g;
            gi = gr[0];
            gf = gr[HH];
            gg = gr[2 * HH];
            go = gr[3 * HH];
        }

        // ---- group barrier: wait for all 64 producers of h(t-1)
        if (tid < 64) {
            while (__hip_atomic_load(gflags + tid, __ATOMIC_RELAXED,
                                     __HIP_MEMORY_SCOPE_AGENT) < (unsigned)t)
                __builtin_amdgcn_s_sleep(1);
        }
        __syncthreads();

        // ---- stage h(t-1)[b0..b0+7][:] -> skewed hs via 16B sc0 loads
        // (L1-bypass, L2-CACHED: same-btile blocks on an XCD share lines).
        {
            const float* hprev = out + (size_t)(t - 1) * BH;
            const float* sp[4];
            int wbi[4], wq[4];
            #pragma unroll
            for (int i = 0; i < 4; ++i) {
                int idx4 = tid + i * 512;          // 0..2047 float4 slots
                wbi[i] = idx4 >> 8;                // 0..7 local b
                wq[i]  = (idx4 & 255) * 4;         // 0..1020, %4==0
                sp[i]  = hprev + (size_t)(b0 + wbi[i]) * HH + wq[i];
            }
            f32x4 v0, v1, v2, v3;
            asm volatile(
                "global_load_dwordx4 %0, %4, off sc0\n\t"
                "global_load_dwordx4 %1, %5, off sc0\n\t"
                "global_load_dwordx4 %2, %6, off sc0\n\t"
                "global_load_dwordx4 %3, %7, off sc0\n\t"
                "s_waitcnt vmcnt(0)"
                : "=&v"(v0), "=&v"(v1), "=&v"(v2), "=&v"(v3)
                : "v"(sp[0]), "v"(sp[1]), "v"(sp[2]), "v"(sp[3])
                : "memory");
            *(f32x4*)&hs[wbi[0] * 1152 + (wq[0] >> 5) * 36 + (wq[0] & 31)] = v0;
            *(f32x4*)&hs[wbi[1] * 1152 + (wq[1] >> 5) * 36 + (wq[1] & 31)] = v1;
            *(f32x4*)&hs[wbi[2] * 1152 + (wq[2] >> 5) * 36 + (wq[2] & 31)] = v2;
            *(f32x4*)&hs[wbi[3] * 1152 + (wq[3] >> 5) * 36 + (wq[3] & 31)] = v3;
        }
        __syncthreads();

        // ---- FMA: acc[8 b][4 gc] over k in [kc*32, kc*32+32)
        // Low-liveness order: per 4-k group load 4 w-rows (16 regs), then
        // per-bi one hv f32x4 (4 regs) -> 16 FMA. Peak ~ acc32+w16+hv4+misc.
        float acc[8][4] = {};
        const float* wp = wbase;
        #pragma unroll 1
        for (int k4 = 0; k4 < 8; ++k4) {
            f32x4 wr0 = *(const f32x4*)(wp);
            f32x4 wr1 = *(const f32x4*)(wp + G4);
            f32x4 wr2 = *(const f32x4*)(wp + 2 * G4);
            f32x4 wr3 = *(const f32x4*)(wp + 3 * G4);
            wp += 4 * G4;
            #pragma unroll
            for (int bi = 0; bi < 8; ++bi) {
                f32x4 hv = *(const f32x4*)&hs[bi * 1152 + hbase + k4 * 4];
                #pragma unroll
                for (int c = 0; c < 4; ++c)
                    acc[bi][c] += hv[0] * wr0[c] + hv[1] * wr1[c]
                                + hv[2] * wr2[c] + hv[3] * wr3[c];
            }
        }
        __syncthreads();                   // hs dead; smem becomes red

        // ---- two rounds (4 b each): stage partials, 32-deep gather.
        // write: red[v][tid] consecutive-tid, conflict-free.
        // read: addr%32 = c*8+ttw (RPAD%32==8) -> exactly 2-way = free.
        #pragma unroll
        for (int round = 0; round < 2; ++round) {
            #pragma unroll
            for (int bi = 0; bi < 4; ++bi)
                #pragma unroll
                for (int c = 0; c < 4; ++c)
                    red[(size_t)(bi * 4 + c) * RPAD + tid] = acc[round * 4 + bi][c];
            __syncthreads();
            if ((tid >> 8) == round) {     // 256 readers = 4 full waves
                const int r2  = tid & 255;
                const int rb  = r2 >> 6;               // b&3
                const int gc  = r2 & 63;               // gate*16 + hc
                const int c   = gc & 3;
                const int ttw = gc >> 2;               // writer tt
                const float* rp = red + (size_t)(rb * 4 + c) * RPAD + ttw;
                float s0 = 0.f, s1 = 0.f, s2 = 0.f, s3 = 0.f;
                #pragma unroll
                for (int k2 = 0; k2 < 32; k2 += 4) {
                    s0 += rp[(k2 + 0) * 16];
                    s1 += rp[(k2 + 1) * 16];
                    s2 += rp[(k2 + 2) * 16];
                    s3 += rp[(k2 + 3) * 16];
                }
                gsum[(round * 4 + rb) * 64 + gc] = (s0 + s1) + (s2 + s3);
            }
            __syncthreads();
        }

        // ---- cell update (thread-local c); publish h through IC
        if (cell_act) {
            float ii = hsig(gi + gsum[cb * 64 + chc]);
            float ff = hsig(gf + gsum[cb * 64 + 16 + chc]);
            float gv = htanh(gg + gsum[cb * 64 + 32 + chc]);
            float oo = hsig(go + gsum[cb * 64 + 48 + chc]);
            creg = ff * creg + ii * gv;
            __hip_atomic_store(out + (size_t)t * BH + cell_h, oo * htanh(creg),
                               __ATOMIC_RELAXED, __HIP_MEMORY_SCOPE_AGENT);
        }
        asm volatile("s_waitcnt vmcnt(0)" ::: "memory");
        __syncthreads();
        if (tid == 0)
            __hip_atomic_store(gflags + hct, (unsigned)(t + 1),
                               __ATOMIC_RELAXED, __HIP_MEMORY_SCOPE_AGENT);
    }
}

// ---------------------------------------------------------------------------
extern "C" void kernel_launch(void* const* d_in, const int* in_sizes, int n_in,
                              void* d_out, int out_size, void* d_ws, size_t ws_size,
                              hipStream_t stream) {
    const float* x  = (const float*)d_in[0];   // [T,B,D]
    const float* Wx = (const float*)d_in[1];   // [D,4H]
    const float* Wh = (const float*)d_in[2];   // [H,4H]
    const float* bs = (const float*)d_in[3];   // [4H]
    float* out = (float*)d_out;                // [T,B,H] — doubles as h history

    // ws layout (floats): Gx 33,554,432 | flags (512 u32)
    float* Gx = (float*)d_ws;
    unsigned* flags = (unsigned*)(Gx + (size_t)MM * G4);

    zero_bar<<<dim3(1), dim3(512), 0, stream>>>(flags);

    // Gx = X @ Wx + b for all timesteps at once
    gx_gemm<<<dim3(G4 / 128, MM / 128), dim3(256), 0, stream>>>(x, Wx, bs, Gx);

    // all 128 recurrent steps in one plain-launch persistent kernel
    lstm_persist<<<dim3(NWG), dim3(512), 0, stream>>>(Gx, Wh, out, flags);
}

// Round 4
// 2470.120 us; speedup vs baseline: 2.3274x; 1.3492x over previous
//
#include <hip/hip_runtime.h>

// Problem constants: T=128, B=64, D=1024, H=1024. fp32 throughout (the
// recurrence is chaotic: per-step gate noise amplifies ~1e3x over 128 steps;
// fp32 order-noise lands at ~4e-3 absmax, bf16 would fail the 2e-2 gate).
#define TT 128
#define BB 64
#define DD 1024
#define HH 1024
#define G4 4096          // 4*H
#define MM (TT*BB)       // 8192 rows of X flattened
#define BH (BB*HH)       // 65536, one timestep of h/out

#define NWG 256          // persistent grid: 1 block per CU (r0 partition —
                         // measured best: r1/r3 showed 2 phase-locked
                         // same-domain blocks/CU contend without overlap)
#define RPAD 520         // red row pad: 520%32==8 -> reader gather 2-way (free)

typedef float f32x4 __attribute__((ext_vector_type(4)));

__device__ __forceinline__ float hsig(float x) {
    x += 0.5f;
    return fminf(fmaxf(x, 0.0f), 1.0f);
}
__device__ __forceinline__ float htanh(float x) {
    return fminf(fmaxf(x, -1.0f), 1.0f);
}

// ---------------------------------------------------------------------------
__global__ void zero_bar(unsigned* p) {
    p[threadIdx.x] = 0u;   // flags[256]
}

// ---------------------------------------------------------------------------
// Gx[8192][4096] = X[8192][1024] @ Wx[1024][4096] + bias  (proven, ~810 us)
__global__ __launch_bounds__(256) void gx_gemm(const float* __restrict__ X,
                                               const float* __restrict__ W,
                                               const float* __restrict__ bias,
                                               float* __restrict__ C) {
    __shared__ float As[16][132];
    __shared__ float Bs[16][132];

    const int tid = threadIdx.x;
    const int tx = tid & 15;
    const int ty = tid >> 4;
    const int m0 = blockIdx.y * 128;
    const int n0 = blockIdx.x * 128;

    float acc[8][8] = {};
    float4 ra[2], rb[2];

    #pragma unroll
    for (int i = 0; i < 2; ++i) {
        int f4 = tid + i * 256;
        ra[i] = *(const float4*)(X + (size_t)(m0 + (f4 >> 2)) * DD + (f4 & 3) * 4);
        rb[i] = *(const float4*)(W + (size_t)(f4 >> 5) * G4 + n0 + (f4 & 31) * 4);
    }

    for (int k0 = 0; k0 < DD; k0 += 16) {
        #pragma unroll
        for (int i = 0; i < 2; ++i) {
            int f4 = tid + i * 256;
            int mi = f4 >> 2, kq = f4 & 3;
            As[kq * 4 + 0][mi] = ra[i].x;
            As[kq * 4 + 1][mi] = ra[i].y;
            As[kq * 4 + 2][mi] = ra[i].z;
            As[kq * 4 + 3][mi] = ra[i].w;
            *(float4*)&Bs[f4 >> 5][(f4 & 31) * 4] = rb[i];
        }
        __syncthreads();

        const int kn = (k0 + 16 < DD) ? (k0 + 16) : k0;
        #pragma unroll
        for (int i = 0; i < 2; ++i) {
            int f4 = tid + i * 256;
            ra[i] = *(const float4*)(X + (size_t)(m0 + (f4 >> 2)) * DD + kn + (f4 & 3) * 4);
            rb[i] = *(const float4*)(W + (size_t)(kn + (f4 >> 5)) * G4 + n0 + (f4 & 31) * 4);
        }

        #pragma unroll
        for (int kk = 0; kk < 16; ++kk) {
            float ar[8], br[8];
            *(float4*)&ar[0] = *(const float4*)&As[kk][ty * 4];
            *(float4*)&ar[4] = *(const float4*)&As[kk][64 + ty * 4];
            *(float4*)&br[0] = *(const float4*)&Bs[kk][tx * 4];
            *(float4*)&br[4] = *(const float4*)&Bs[kk][64 + tx * 4];
            #pragma unroll
            for (int i = 0; i < 8; ++i)
                #pragma unroll
                for (int j = 0; j < 8; ++j)
                    acc[i][j] += ar[i] * br[j];
        }
        __syncthreads();
    }

    float bl[8];
    *(float4*)&bl[0] = *(const float4*)(bias + n0 + tx * 4);
    *(float4*)&bl[4] = *(const float4*)(bias + n0 + 64 + tx * 4);
    #pragma unroll
    for (int i = 0; i < 8; ++i) {
        int mrow = m0 + ty * 4 + (i & 3) + 64 * (i >> 2);
        float* crow = C + (size_t)mrow * G4 + n0;
        float4 o1, o2;
        o1.x = acc[i][0] + bl[0]; o1.y = acc[i][1] + bl[1];
        o1.z = acc[i][2] + bl[2]; o1.w = acc[i][3] + bl[3];
        o2.x = acc[i][4] + bl[4]; o2.y = acc[i][5] + bl[5];
        o2.z = acc[i][6] + bl[6]; o2.w = acc[i][7] + bl[7];
        *(float4*)(crow + tx * 4) = o1;
        *(float4*)(crow + 64 + tx * 4) = o2;
    }
}

// ---------------------------------------------------------------------------
// Persistent recurrence — r0 partition (measured best: 15.4 us/step), plus
// two surgical fixes isolated by rounds 1-3:
//  (1) conflict-free reduction (r0's reduce carried 6.76e7 bank-conflict
//      cycles ~= 0.85 us/step; r3's red[vidx][RPAD] layout cut it 67x).
//  (2) per-producer streamed staging: each thread polls ONLY its producer's
//      flag, then immediately issues its 64B of sc0 16B loads. Early
//      producers' h is staged while stragglers still compute — removes the
//      "wait for ALL 32 flags, then stage" serialization of r0.
// Partition: 256 wgs = 8 btiles (8 batch rows) x 32 hcts (32 H-cols). 1
// block/CU; co-residency games are over (r1/r3: same-domain co-resident
// blocks are phase-locked -> contention, no overlap).
// FENCE-FREE cross-wg h exchange: agent-scope relaxed stores + sc0
// (L2-cached, L1-bypassed) loads served via L2/IC. Consumer-L2 lines for
// out[t-1] are always cold before the flag-gated read (producers write
// through; reads happen only post-flag), so L2 caching is safe and
// same-btile blocks on an XCD share staged lines (r0: 206 MB FETCH total;
// r2's sc1 bypass cost 2.44 GB).
// Ordering: h stores -> s_waitcnt vmcnt(0) -> __syncthreads -> flag store.
// NOTE __launch_bounds__: single arg only. 2nd arg is min BLOCKS/CU on this
// toolchain (r1: (512,4) -> VGPR capped 64 -> scratch spill disaster).
__global__ __launch_bounds__(512) void lstm_persist(const float* __restrict__ Gx,
                                                    const float* __restrict__ Wh,
                                                    float* __restrict__ out,
                                                    unsigned* __restrict__ flags) {
    // union: hs = [8 b][1152] = 9216 | red = [32 vidx][520] = 16640 ; +gsum[1024]
    // total 17664 floats = 70.7 KB (1 block/CU: LDS is not a constraint).
    __shared__ float smem[16640 + 1024];
    float* hs   = smem;
    float* red  = smem;
    float* gsum = smem + 16640;

    const int tid   = threadIdx.x;
    const int btile = blockIdx.x >> 5;     // 0..7
    const int hct   = blockIdx.x & 31;     // 0..31
    const int b0  = btile * 8;
    const int hc0 = hct * 32;

    // matmul identity (r0-proven): kc = 32-k chunk (0..31), tt = 8 gate-cols
    const int kc = tid >> 4;
    const int tt = tid & 15;
    const int gate_m = tt >> 2;            // 0..3
    const int sub8 = (tt & 3) * 8;         // 0,8,16,24 within the 32-col block
    const float* wbase = Wh + (size_t)(kc * 32) * G4 + gate_m * HH + hc0 + sub8;

    // staging identity: 16 threads per producer, 64B contiguous each
    const int pp  = tid >> 4;              // producer 0..31
    const int ss  = tid & 15;
    const int srow = ss >> 1;              // 0..7 local b row
    const int cq0  = (ss & 1) * 4;         // first of 4 consecutive f32x4 slots

    // cell identity (tid<256): one (b, hcol) cell per thread, c in creg
    const bool cell_act = (tid < 256);
    const int cb  = tid >> 5;              // 0..7 local b
    const int chc = tid & 31;              // 0..31 local h col
    const size_t cell_g = (size_t)(b0 + cb) * G4 + hc0 + chc;
    const size_t cell_h = (size_t)(b0 + cb) * HH + hc0 + chc;
    float creg = 0.0f;

    // reduction reader identity: 512 readers, one (b, gate-col) sum each
    const int rb_ = tid >> 7;              // 0..3 round-local b
    const int rgc = tid & 127;             // gate-col 0..127 (= tt*8 + j)
    const int rtt = rgc >> 3;              // writer tt
    const int rj  = rgc & 7;               // writer j

    unsigned* gflags = flags + btile * 32; // this btile group's 32 flags

    // ---- t = 0: gates = Gx[0] (h0 = c0 = 0); publish h(0) through IC
    if (cell_act) {
        const float* gr = Gx + cell_g;
        float ii = hsig(gr[0]);
        float gv = htanh(gr[2 * HH]);
        float oo = hsig(gr[3 * HH]);
        creg = ii * gv;
        __hip_atomic_store(out + cell_h, oo * htanh(creg),
                           __ATOMIC_RELAXED, __HIP_MEMORY_SCOPE_AGENT);
    }
    asm volatile("s_waitcnt vmcnt(0)" ::: "memory");
    __syncthreads();
    if (tid == 0)
        __hip_atomic_store(gflags + hct, 1u, __ATOMIC_RELAXED,
                           __HIP_MEMORY_SCOPE_AGENT);

    for (int t = 1; t < TT; ++t) {
        // prefetch this step's Gx gate values (own data; overlaps the wait)
        float gi = 0.f, gf = 0.f, gg = 0.f, go = 0.f;
        if (cell_act) {
            const float* gr = Gx + (size_t)t * BB * G4 + cell_g;
            gi = gr[0];
            gf = gr[HH];
            gg = gr[2 * HH];
            go = gr[3 * HH];
        }

        // ---- streamed stage: poll OWN producer's flag, then immediately
        // load this thread's 64B slice (4 x 16B sc0, L2-cached) -> skewed hs.
        {
            while (__hip_atomic_load(gflags + pp, __ATOMIC_RELAXED,
                                     __HIP_MEMORY_SCOPE_AGENT) < (unsigned)t)
                __builtin_amdgcn_s_sleep(1);

            const float* hp = out + (size_t)(t - 1) * BH
                            + (size_t)(b0 + srow) * HH + pp * 32 + cq0 * 4;
            f32x4 v0, v1, v2, v3;
            asm volatile(
                "global_load_dwordx4 %0, %4, off sc0\n\t"
                "global_load_dwordx4 %1, %4, off offset:16 sc0\n\t"
                "global_load_dwordx4 %2, %4, off offset:32 sc0\n\t"
                "global_load_dwordx4 %3, %4, off offset:48 sc0\n\t"
                "s_waitcnt vmcnt(0)"
                : "=&v"(v0), "=&v"(v1), "=&v"(v2), "=&v"(v3)
                : "v"(hp)
                : "memory");
            float* hd = &hs[srow * 1152 + pp * 36 + cq0 * 4];
            *(f32x4*)(hd)      = v0;
            *(f32x4*)(hd + 4)  = v1;
            *(f32x4*)(hd + 8)  = v2;
            *(f32x4*)(hd + 12) = v3;
        }
        __syncthreads();

        // ---- FMA: acc[8 b][8 gc] over k in [kc*32, kc*32+32)  (r0-proven)
        float acc[8][8] = {};
        const float* wp = wbase;
        #pragma unroll 2
        for (int k4 = 0; k4 < 8; ++k4) {
            f32x4 hv[8];
            #pragma unroll
            for (int bi = 0; bi < 8; ++bi)
                hv[bi] = *(const f32x4*)&hs[bi * 1152 + kc * 36 + k4 * 4];
            #pragma unroll
            for (int j = 0; j < 4; ++j) {
                f32x4 w0 = *(const f32x4*)(wp);
                f32x4 w1 = *(const f32x4*)(wp + 4);
                wp += G4;
                #pragma unroll
                for (int bi = 0; bi < 8; ++bi) {
                    float h = hv[bi][j];
                    acc[bi][0] += h * w0[0];
                    acc[bi][1] += h * w0[1];
                    acc[bi][2] += h * w0[2];
                    acc[bi][3] += h * w0[3];
                    acc[bi][4] += h * w1[0];
                    acc[bi][5] += h * w1[1];
                    acc[bi][6] += h * w1[2];
                    acc[bi][7] += h * w1[3];
                }
            }
        }
        __syncthreads();                   // hs dead; smem becomes red

        // ---- two rounds (4 b each): conflict-free reduce (r3-proven
        // layout). write red[vidx][tid]: consecutive-tid, conflict-free.
        // read stride 16, RPAD%32==8 -> every bank hit by exactly 2 lanes.
        #pragma unroll
        for (int round = 0; round < 2; ++round) {
            #pragma unroll
            for (int bi = 0; bi < 4; ++bi)
                #pragma unroll
                for (int j = 0; j < 8; ++j)
                    red[(size_t)(bi * 8 + j) * RPAD + tid] = acc[round * 4 + bi][j];
            __syncthreads();
            {   // 512 readers, one (rb_, rgc) sum each over 32 kc partials
                const float* rp = red + (size_t)(rb_ * 8 + rj) * RPAD + rtt;
                float s0 = 0.f, s1 = 0.f, s2 = 0.f, s3 = 0.f;
                #pragma unroll
                for (int k2 = 0; k2 < 32; k2 += 4) {
                    s0 += rp[(k2 + 0) * 16];
                    s1 += rp[(k2 + 1) * 16];
                    s2 += rp[(k2 + 2) * 16];
                    s3 += rp[(k2 + 3) * 16];
                }
                gsum[(round * 4 + rb_) * 128 + rgc] = (s0 + s1) + (s2 + s3);
            }
            __syncthreads();
        }

        // ---- cell update (thread-local c); publish h through IC
        if (cell_act) {
            float ii = hsig(gi + gsum[cb * 128 + chc]);
            float ff = hsig(gf + gsum[cb * 128 + 32 + chc]);
            float gv = htanh(gg + gsum[cb * 128 + 64 + chc]);
            float oo = hsig(go + gsum[cb * 128 + 96 + chc]);
            creg = ff * creg + ii * gv;
            __hip_atomic_store(out + (size_t)t * BH + cell_h, oo * htanh(creg),
                               __ATOMIC_RELAXED, __HIP_MEMORY_SCOPE_AGENT);
        }
        asm volatile("s_waitcnt vmcnt(0)" ::: "memory");
        __syncthreads();
        if (tid == 0)
            __hip_atomic_store(gflags + hct, (unsigned)(t + 1),
                               __ATOMIC_RELAXED, __HIP_MEMORY_SCOPE_AGENT);
    }
}

// ---------------------------------------------------------------------------
extern "C" void kernel_launch(void* const* d_in, const int* in_sizes, int n_in,
                              void* d_out, int out_size, void* d_ws, size_t ws_size,
                              hipStream_t stream) {
    const float* x  = (const float*)d_in[0];   // [T,B,D]
    const float* Wx = (const float*)d_in[1];   // [D,4H]
    const float* Wh = (const float*)d_in[2];   // [H,4H]
    const float* bs = (const float*)d_in[3];   // [4H]
    float* out = (float*)d_out;                // [T,B,H] — doubles as h history

    // ws layout (floats): Gx 33,554,432 | flags (256 u32)
    float* Gx = (float*)d_ws;
    unsigned* flags = (unsigned*)(Gx + (size_t)MM * G4);

    zero_bar<<<dim3(1), dim3(256), 0, stream>>>(flags);

    // Gx = X @ Wx + b for all timesteps at once
    gx_gemm<<<dim3(G4 / 128, MM / 128), dim3(256), 0, stream>>>(x, Wx, bs, Gx);

    // all 128 recurrent steps in one plain-launch persistent kernel
    lstm_persist<<<dim3(NWG), dim3(512), 0, stream>>>(Gx, Wh, out, flags);
}